// Round 4
// baseline (269.723 us; speedup 1.0000x reference)
//
#include <hip/hip_runtime.h>

// QattenNet: B=E*T=8192, S=256, A=32, O=128, QH1=128, QD=64, C1=128, H=4.
// Algebra: out[b] = sum_a q[b,a] * (f[b,a,:]·v[b,:]) + beta[b]*sumq[b] + c[b]
//   v[b,o]  = sum_k WkT[k,o] * emb[b,k],  WkT[k,o] = sum_h Wk[h,o,k]
//   emb     = relu(s@Wq1+bq1) @ Wq2 + bq2
//   beta[b] = emb[b,:]·bkSum,             bkSum[k] = sum_h bk[h,k]
//   c[b]    = relu(s@Wc1+bc1)·Wc2 + bc2
//
// R4: NB=4, grid=2048, LDS ~11.9 KB, launch_bounds(256,8) -> 8 blocks/CU
// (32 waves/CU, 8 waves/SIMD). R3 at 4 blocks/CU was latency-bound
// (VALUBusy 28% == 4 waves x 60cyc / 600cyc stall window).

static constexpr int Sd  = 256;
static constexpr int Ad  = 32;
static constexpr int Od  = 128;
static constexpr int QDd = 64;
static constexpr int NB  = 4;

__global__ void qatten_prep(const float* __restrict__ Wk, const float* __restrict__ bk,
                            float* __restrict__ WkT, float* __restrict__ bkSum)
{
    int idx = blockIdx.x * 256 + threadIdx.x;   // 0..8191
    int k = idx >> 7;          // 0..63
    int o = idx & 127;         // 0..127
    float s = 0.f;
#pragma unroll
    for (int h = 0; h < 4; ++h) s += Wk[h * (Od * QDd) + o * QDd + k];
    WkT[k * Od + o] = s;
    if (idx < QDd) {
        float t = 0.f;
#pragma unroll
        for (int h = 0; h < 4; ++h) t += bk[h * QDd + idx];
        bkSum[idx] = t;
    }
}

__global__ __launch_bounds__(256, 8) void qatten_fused(
    const float* __restrict__ qv, const float* __restrict__ st, const float* __restrict__ fs,
    const float* __restrict__ Wq1, const float* __restrict__ bq1,
    const float* __restrict__ Wq2, const float* __restrict__ bq2,
    const float* __restrict__ Wc1, const float* __restrict__ bc1,
    const float* __restrict__ Wc2, const float* __restrict__ bc2,
    const float* __restrict__ WkT, const float* __restrict__ bkSum,
    float* __restrict__ out)
{
    __shared__ float s_lds[NB][Sd];     // 4 KB
    __shared__ float h_lds[NB][260];    // 4.06 KB (cols 0-127: h1, 128-255: hc)
    __shared__ float emb_lds[NB][QDd];  // 1 KB
    __shared__ float v_lds[NB][Od];     // 2 KB
    __shared__ float q_lds[NB][Ad];     // 0.5 KB
    __shared__ float red_lds[NB][4];    // 64 B
    __shared__ float bias_lds[NB];      // 16 B   total ~11.9 KB

    const int tid = threadIdx.x;
    const int b0 = blockIdx.x * NB;

    // ---- phase 0: stage s (4x256) and q (4x32), coalesced ----
    {
        const float4* sp = (const float4*)(st + (size_t)b0 * Sd);
        ((float4*)&s_lds[0][0])[tid] = sp[tid];
        if (tid < NB * Ad) (&q_lds[0][0])[tid] = qv[(size_t)b0 * Ad + tid];
    }
    __syncthreads();

    // ---- phase 2: h = relu(s @ [Wq1|Wc1] + [bq1|bc1]); thread = 1 col x 4 rows ----
    // weight loads coalesced across lanes; identical addresses across the 8
    // sibling blocks on a CU -> L1-served. s is wave-uniform LDS broadcast.
    {
        const float* W  = (tid < 128) ? (Wq1 + tid) : (Wc1 + (tid - 128));
        const float  bb = (tid < 128) ? bq1[tid] : bc1[tid - 128];
        float acc[NB];
#pragma unroll
        for (int r = 0; r < NB; ++r) acc[r] = 0.f;
#pragma unroll 4
        for (int i = 0; i < Sd; i += 4) {
            const float w0 = W[(size_t)(i + 0) * 128];
            const float w1 = W[(size_t)(i + 1) * 128];
            const float w2 = W[(size_t)(i + 2) * 128];
            const float w3 = W[(size_t)(i + 3) * 128];
#pragma unroll
            for (int r = 0; r < NB; ++r) {
                const float4 sv = *(const float4*)&s_lds[r][i];
                float a = acc[r];
                a = fmaf(sv.x, w0, a);
                a = fmaf(sv.y, w1, a);
                a = fmaf(sv.z, w2, a);
                a = fmaf(sv.w, w3, a);
                acc[r] = a;
            }
        }
#pragma unroll
        for (int r = 0; r < NB; ++r)
            h_lds[r][tid] = fmaxf(acc[r] + bb, 0.f);
    }
    __syncthreads();

    // ---- phase 3: emb = h1 @ Wq2 + bq2; thread = 1 col x 1 row ----
    {
        const int k = tid & 63;
        const int r = tid >> 6;         // 0..3
        float a0 = 0.f;
#pragma unroll 4
        for (int j = 0; j < 128; j += 4) {
            const float w0 = Wq2[(size_t)(j + 0) * 64 + k];
            const float w1 = Wq2[(size_t)(j + 1) * 64 + k];
            const float w2 = Wq2[(size_t)(j + 2) * 64 + k];
            const float w3 = Wq2[(size_t)(j + 3) * 64 + k];
            const float4 hv = *(const float4*)&h_lds[r][j];
            a0 = fmaf(hv.x, w0, a0);
            a0 = fmaf(hv.y, w1, a0);
            a0 = fmaf(hv.z, w2, a0);
            a0 = fmaf(hv.w, w3, a0);
        }
        emb_lds[r][k] = a0 + bq2[k];
    }
    __syncthreads();

    // ---- phase 4: v = emb @ WkT; thread = 1 col x 2 rows ----
    {
        const int o = tid & 127;
        const int rg = (tid >> 7) * 2;  // rows rg, rg+1
        float a0 = 0.f, a1 = 0.f;
#pragma unroll 4
        for (int k = 0; k < QDd; k += 4) {
            const float w0 = WkT[(size_t)(k + 0) * 128 + o];
            const float w1 = WkT[(size_t)(k + 1) * 128 + o];
            const float w2 = WkT[(size_t)(k + 2) * 128 + o];
            const float w3 = WkT[(size_t)(k + 3) * 128 + o];
            const float4 e0 = *(const float4*)&emb_lds[rg][k];
            const float4 e1 = *(const float4*)&emb_lds[rg + 1][k];
            a0 = fmaf(e0.x, w0, a0);  a1 = fmaf(e1.x, w0, a1);
            a0 = fmaf(e0.y, w1, a0);  a1 = fmaf(e1.y, w1, a1);
            a0 = fmaf(e0.z, w2, a0);  a1 = fmaf(e1.z, w2, a1);
            a0 = fmaf(e0.w, w3, a0);  a1 = fmaf(e1.w, w3, a1);
        }
        v_lds[rg][o] = a0;
        v_lds[rg + 1][o] = a1;
    }

    // ---- phase 5: bias[b] = c[b] + beta[b]*sumq[b]; one wave per b ----
    // reads emb_lds (synced after ph3) and h_lds cols 128+ (synced after ph2).
    {
        const int b = tid >> 6;         // 0..3 (wave index)
        const int i = tid & 63;
        float pb = (i < QDd) ? emb_lds[b][i] * bkSum[i] : 0.f;
        float pc = h_lds[b][128 + i] * Wc2[i] + h_lds[b][128 + 64 + i] * Wc2[64 + i];
        float pq = (i < Ad) ? q_lds[b][i] : 0.f;
#pragma unroll
        for (int d = 32; d >= 1; d >>= 1) {
            pb += __shfl_xor(pb, d);
            pc += __shfl_xor(pc, d);
            pq += __shfl_xor(pq, d);
        }
        if (i == 0) bias_lds[b] = (pc + bc2[0]) + pb * pq;
    }
    __syncthreads();   // covers ph4 v_lds writes and ph5 bias writes

    // ---- phase 6: stream f; thread = (oq over O-quads, ag over agents) ----
    {
        const int oq = tid & 31;        // float4 slot over O
        const int ag = tid >> 5;        // 0..7
        float acc[NB];
#pragma unroll
        for (int b = 0; b < NB; ++b) {
            const float4* fb = (const float4*)(fs + (size_t)(b0 + b) * (Ad * Od));
            const float4 v4 = *(const float4*)&v_lds[b][oq * 4];
            float s = 0.f;
#pragma unroll
            for (int r = 0; r < 4; ++r) {
                const int a = ag + 8 * r;
                const float4 f4 = fb[a * 32 + oq];
                float d = f4.x * v4.x;
                d = fmaf(f4.y, v4.y, d);
                d = fmaf(f4.z, v4.z, d);
                d = fmaf(f4.w, v4.w, d);
                s = fmaf(q_lds[b][a], d, s);
            }
            acc[b] = s;
        }
        const int lane = tid & 63;
        const int wv = tid >> 6;
#pragma unroll
        for (int b = 0; b < NB; ++b) {
            float s = acc[b];
#pragma unroll
            for (int d = 32; d >= 1; d >>= 1) s += __shfl_xor(s, d);
            acc[b] = s;
        }
        if (lane == 0) {
#pragma unroll
            for (int b = 0; b < NB; ++b) red_lds[b][wv] = acc[b];
        }
    }
    __syncthreads();

    // ---- final: out[b] = sum of 4 wave partials + bias[b] ----
    if (tid < NB) {
        out[b0 + tid] = red_lds[tid][0] + red_lds[tid][1] +
                        red_lds[tid][2] + red_lds[tid][3] + bias_lds[tid];
    }
}

extern "C" void kernel_launch(void* const* d_in, const int* in_sizes, int n_in,
                              void* d_out, int out_size, void* d_ws, size_t ws_size,
                              hipStream_t stream) {
    const float* qv  = (const float*)d_in[0];
    const float* st  = (const float*)d_in[1];
    const float* fs  = (const float*)d_in[2];
    const float* Wq1 = (const float*)d_in[3];
    const float* bq1 = (const float*)d_in[4];
    const float* Wq2 = (const float*)d_in[5];
    const float* bq2 = (const float*)d_in[6];
    const float* Wk  = (const float*)d_in[7];
    const float* bk  = (const float*)d_in[8];
    const float* Wc1 = (const float*)d_in[9];
    const float* bc1 = (const float*)d_in[10];
    const float* Wc2 = (const float*)d_in[11];
    const float* bc2 = (const float*)d_in[12];
    float* out = (float*)d_out;

    float* WkT   = (float*)d_ws;            // 64*128 floats
    float* bkSum = WkT + QDd * Od;          // 64 floats

    qatten_prep<<<32, 256, 0, stream>>>(Wk, bk, WkT, bkSum);
    qatten_fused<<<2048, 256, 0, stream>>>(qv, st, fs, Wq1, bq1, Wq2, bq2,
                                           Wc1, bc1, Wc2, bc2, WkT, bkSum, out);
}

// Round 5
// 268.686 us; speedup vs baseline: 1.0039x; 1.0039x over previous
//
#include <hip/hip_runtime.h>

// QattenNet: B=E*T=8192, S=256, A=32, O=128, QH1=128, QD=64, C1=128, H=4.
// out[b] = sum_a q[b,a]*(f[b,a,:]·v[b,:]) + beta[b]*sumq[b] + c[b]
// Fold:  M = Wq2@WkT (128x128), v0 = bq2@WkT, m_beta = Wq2@bkSum, beta0 = bq2·bkSum
//   h1|hc = relu(s@[Wq1|Wc1] + [bq1|bc1])
//   v[b]  = h1[b]@M + v0        (emb eliminated by associativity)
//   beta  = h1[b]·m_beta + beta0
//   c[b]  = hc[b]·Wc2 + bc2
//
// R5: clean split. MLP kernel NB=16 (weight traffic ~165MB, VALU-bound);
// stream kernel = one wave per b, no LDS, no syncs, 16 independent 1KB loads.

static constexpr int Sd  = 256;
static constexpr int Ad  = 32;
static constexpr int Od  = 128;
static constexpr int QDd = 64;

// d_ws float offsets
static constexpr size_t WS_WKT   = 0;        // 64*128
static constexpr size_t WS_BKSUM = 8192;     // 64
static constexpr size_t WS_M     = 8256;     // 128*128
static constexpr size_t WS_V0    = 24640;    // 128
static constexpr size_t WS_MBETA = 24768;    // 128
static constexpr size_t WS_BETA0 = 24896;    // 1
static constexpr size_t WS_BIAS  = 24960;    // 8192
static constexpr size_t WS_V     = 33216;    // 8192*128  (33216*4 % 16 == 0)

__global__ void qatten_prep1(const float* __restrict__ Wk, const float* __restrict__ bk,
                             float* __restrict__ WkT, float* __restrict__ bkSum)
{
    int idx = blockIdx.x * 256 + threadIdx.x;   // 0..8191
    int k = idx >> 7;          // 0..63
    int o = idx & 127;         // 0..127
    float s = 0.f;
#pragma unroll
    for (int h = 0; h < 4; ++h) s += Wk[h * (Od * QDd) + o * QDd + k];
    WkT[k * Od + o] = s;
    if (idx < QDd) {
        float t = 0.f;
#pragma unroll
        for (int h = 0; h < 4; ++h) t += bk[h * QDd + idx];
        bkSum[idx] = t;
    }
}

__global__ void qatten_prep2(const float* __restrict__ Wq2, const float* __restrict__ bq2,
                             const float* __restrict__ WkT, const float* __restrict__ bkSum,
                             float* __restrict__ M, float* __restrict__ v0,
                             float* __restrict__ m_beta, float* __restrict__ beta0)
{
    int idx = blockIdx.x * 256 + threadIdx.x;   // 0..16383
    int j = idx >> 7;          // 0..127
    int o = idx & 127;         // 0..127
    float acc = 0.f;
    for (int k = 0; k < QDd; ++k)
        acc = fmaf(Wq2[j * QDd + k], WkT[k * Od + o], acc);
    M[j * Od + o] = acc;
    if (idx < 128) {
        float a = 0.f;
        for (int k = 0; k < QDd; ++k) a = fmaf(bq2[k], WkT[k * Od + idx], a);
        v0[idx] = a;
    } else if (idx < 256) {
        const int jj = idx - 128;
        float a = 0.f;
        for (int k = 0; k < QDd; ++k) a = fmaf(Wq2[jj * QDd + k], bkSum[k], a);
        m_beta[jj] = a;
    }
    if (idx == 0) {
        float a = 0.f;
        for (int k = 0; k < QDd; ++k) a = fmaf(bq2[k], bkSum[k], a);
        beta0[0] = a;
    }
}

// NB=16 rows/block, grid 512. LDS ~34 KB -> 2-4 blocks/CU. Weight loads
// amortized over 16 rows; s/h reads are wave-uniform LDS broadcasts.
static constexpr int NBM = 16;

__global__ __launch_bounds__(256, 4) void qatten_mlp(
    const float* __restrict__ qv, const float* __restrict__ st,
    const float* __restrict__ Wq1, const float* __restrict__ bq1,
    const float* __restrict__ Wc1, const float* __restrict__ bc1,
    const float* __restrict__ Wc2, const float* __restrict__ bc2,
    const float* __restrict__ M, const float* __restrict__ v0,
    const float* __restrict__ m_beta, const float* __restrict__ beta0p,
    float* __restrict__ v_ws, float* __restrict__ bias_ws)
{
    __shared__ float s_lds[NBM][Sd];    // 16 KB
    __shared__ float h_lds[NBM][258];   // 16.1 KB (0-127: h1, 128-255: hc)
    __shared__ float q_lds[NBM][Ad];    // 2 KB

    const int tid = threadIdx.x;
    const int b0 = blockIdx.x * NBM;

    // stage s (16x256) and q (16x32), coalesced
    {
        const float4* sp = (const float4*)(st + (size_t)b0 * Sd);
        float4* sl = (float4*)&s_lds[0][0];
#pragma unroll
        for (int i = 0; i < 4; ++i) sl[tid + i * 256] = sp[tid + i * 256];
        float* ql = &q_lds[0][0];
#pragma unroll
        for (int i = 0; i < 2; ++i) ql[tid + i * 256] = qv[(size_t)b0 * Ad + tid + i * 256];
    }
    __syncthreads();

    // h = relu(s @ [Wq1|Wc1] + bias); thread = 1 col x 16 rows
    {
        const float* W  = (tid < 128) ? (Wq1 + tid) : (Wc1 + (tid - 128));
        const float  bb = (tid < 128) ? bq1[tid] : bc1[tid - 128];
        float acc[NBM];
#pragma unroll
        for (int r = 0; r < NBM; ++r) acc[r] = 0.f;
        for (int i = 0; i < Sd; i += 4) {
            const float w0 = W[(size_t)(i + 0) * 128];
            const float w1 = W[(size_t)(i + 1) * 128];
            const float w2 = W[(size_t)(i + 2) * 128];
            const float w3 = W[(size_t)(i + 3) * 128];
#pragma unroll
            for (int r = 0; r < NBM; ++r) {
                const float4 sv = *(const float4*)&s_lds[r][i];   // wave-uniform broadcast
                float a = acc[r];
                a = fmaf(sv.x, w0, a);
                a = fmaf(sv.y, w1, a);
                a = fmaf(sv.z, w2, a);
                a = fmaf(sv.w, w3, a);
                acc[r] = a;
            }
        }
#pragma unroll
        for (int r = 0; r < NBM; ++r)
            h_lds[r][tid] = fmaxf(acc[r] + bb, 0.f);
    }
    __syncthreads();

    // v[b] = h1[b] @ M + v0; thread = 1 col o x 8 rows
    {
        const int o = tid & 127;
        const int rg = (tid >> 7) * 8;   // rows rg..rg+7
        float acc[8];
#pragma unroll
        for (int r = 0; r < 8; ++r) acc[r] = 0.f;
        for (int j = 0; j < 128; j += 4) {
            const float m0 = M[(size_t)(j + 0) * 128 + o];
            const float m1 = M[(size_t)(j + 1) * 128 + o];
            const float m2 = M[(size_t)(j + 2) * 128 + o];
            const float m3 = M[(size_t)(j + 3) * 128 + o];
#pragma unroll
            for (int r = 0; r < 8; ++r) {
                const float4 hv = *(const float4*)&h_lds[rg + r][j];  // broadcast
                float a = acc[r];
                a = fmaf(hv.x, m0, a);
                a = fmaf(hv.y, m1, a);
                a = fmaf(hv.z, m2, a);
                a = fmaf(hv.w, m3, a);
                acc[r] = a;
            }
        }
        const float v0o = v0[o];
#pragma unroll
        for (int r = 0; r < 8; ++r)
            v_ws[(size_t)(b0 + rg + r) * 128 + o] = acc[r] + v0o;
    }

    // bias[b] = (hc[b]·Wc2 + bc2) + (h1[b]·m_beta + beta0) * sumq[b]
    // h_lds/q_lds valid after earlier syncs; 16 lanes per row.
    {
        const int b = tid >> 4;
        const int i = tid & 15;
        float pb = 0.f, pc = 0.f;
#pragma unroll
        for (int t = 0; t < 8; ++t) {
            const int j = i + 16 * t;
            pb = fmaf(h_lds[b][j], m_beta[j], pb);
            pc = fmaf(h_lds[b][128 + j], Wc2[j], pc);
        }
        float pq = q_lds[b][i] + q_lds[b][i + 16];
#pragma unroll
        for (int d = 8; d >= 1; d >>= 1) {
            pb += __shfl_down(pb, d, 16);
            pc += __shfl_down(pc, d, 16);
            pq += __shfl_down(pq, d, 16);
        }
        if (i == 0) bias_ws[b0 + b] = (pc + bc2[0]) + (pb + beta0p[0]) * pq;
    }
}

// One wave per b: 16 independent 1KB-contiguous loads, in-wave butterfly
// reduce, no LDS, no __syncthreads. grid 2048 x 256 -> 8192 waves.
__global__ __launch_bounds__(256, 8) void qatten_stream(
    const float* __restrict__ qv, const float* __restrict__ fs,
    const float* __restrict__ v_ws, const float* __restrict__ bias_ws,
    float* __restrict__ out)
{
    const int gw   = (blockIdx.x * 256 + threadIdx.x) >> 6;   // b = global wave id
    const int lane = threadIdx.x & 63;
    const int oq   = lane & 31;
    const int a0   = lane >> 5;

    const float4* fb = (const float4*)(fs + (size_t)gw * (Ad * Od));
    const float4  v4 = *(const float4*)(v_ws + (size_t)gw * Od + oq * 4);
    const float*  qb = qv + (size_t)gw * Ad;

    float s = 0.f;
#pragma unroll
    for (int r = 0; r < 16; ++r) {
        const int a = a0 + 2 * r;
        const float4 f4 = fb[a * 32 + oq];      // wave covers 1KB contiguous
        float d = f4.x * v4.x;
        d = fmaf(f4.y, v4.y, d);
        d = fmaf(f4.z, v4.z, d);
        d = fmaf(f4.w, v4.w, d);
        s = fmaf(qb[a], d, s);
    }
#pragma unroll
    for (int d = 32; d >= 1; d >>= 1) s += __shfl_xor(s, d);
    if (lane == 0) out[gw] = s + bias_ws[gw];
}

extern "C" void kernel_launch(void* const* d_in, const int* in_sizes, int n_in,
                              void* d_out, int out_size, void* d_ws, size_t ws_size,
                              hipStream_t stream) {
    const float* qv  = (const float*)d_in[0];
    const float* st  = (const float*)d_in[1];
    const float* fs  = (const float*)d_in[2];
    const float* Wq1 = (const float*)d_in[3];
    const float* bq1 = (const float*)d_in[4];
    const float* Wq2 = (const float*)d_in[5];
    const float* bq2 = (const float*)d_in[6];
    const float* Wk  = (const float*)d_in[7];
    const float* bk  = (const float*)d_in[8];
    const float* Wc1 = (const float*)d_in[9];
    const float* bc1 = (const float*)d_in[10];
    const float* Wc2 = (const float*)d_in[11];
    const float* bc2 = (const float*)d_in[12];
    float* out = (float*)d_out;

    float* ws      = (float*)d_ws;
    float* WkT     = ws + WS_WKT;
    float* bkSum   = ws + WS_BKSUM;
    float* Mm      = ws + WS_M;
    float* v0      = ws + WS_V0;
    float* m_beta  = ws + WS_MBETA;
    float* beta0   = ws + WS_BETA0;
    float* bias_ws = ws + WS_BIAS;
    float* v_ws    = ws + WS_V;

    qatten_prep1<<<32, 256, 0, stream>>>(Wk, bk, WkT, bkSum);
    qatten_prep2<<<64, 256, 0, stream>>>(Wq2, bq2, WkT, bkSum, Mm, v0, m_beta, beta0);
    qatten_mlp<<<512, 256, 0, stream>>>(qv, st, Wq1, bq1, Wc1, bc1, Wc2, bc2,
                                        Mm, v0, m_beta, beta0, v_ws, bias_ws);
    qatten_stream<<<2048, 256, 0, stream>>>(qv, fs, v_ws, bias_ws, out);
}

// Round 6
// 260.364 us; speedup vs baseline: 1.0359x; 1.0320x over previous
//
#include <hip/hip_runtime.h>

// QattenNet: B=E*T=8192, S=256, A=32, O=128, QH1=128, QD=64, C1=128, H=4.
// out[b] = sum_a q[b,a]*(f[b,a,:]·v[b,:]) + beta[b]*sumq[b] + c[b]
// Folds (prep): WkT[k,o]=sum_h Wk[h,o,k]; M = Wq2@WkT (128x128); v0 = bq2@WkT;
//               m_beta = Wq2@bkSum; beta0 = bq2·bkSum
//   h1|hc = relu(s@[Wq1|Wc1] + [bq1|bc1])
//   v[b]  = h1[b]@M + v0 ;  beta = h1·m_beta + beta0 ;  c = hc·Wc2 + bc2
//
// R6: fused NB=8/grid1024 (best known) + lgkmcnt-only barriers (keep VMEM in
// flight across phases; all inter-phase comms are LDS) + f register prefetch:
// 16 float4 (b0..3) at top, 8 (b4,5) mid — half the f-stream overlaps the MLP.

static constexpr int Sd  = 256;
static constexpr int Ad  = 32;
static constexpr int Od  = 128;
static constexpr int QDd = 64;
static constexpr int NB  = 8;

// d_ws float offsets
static constexpr size_t WS_WKT   = 0;        // 64*128
static constexpr size_t WS_BKSUM = 8192;     // 64
static constexpr size_t WS_M     = 8256;     // 128*128
static constexpr size_t WS_V0    = 24640;    // 128
static constexpr size_t WS_MBETA = 24768;    // 128
static constexpr size_t WS_BETA0 = 24896;    // 1

// barrier that waits only on LDS ops: does NOT drain outstanding global loads.
// Correct here because all cross-wave data flows through LDS (no global stores
// before the epilogue). 0xc07f = vmcnt(63) expcnt(7) lgkmcnt(0).
__device__ __forceinline__ void barrier_lds() {
    asm volatile("" ::: "memory");
    __builtin_amdgcn_s_waitcnt(0xc07f);
    __builtin_amdgcn_s_barrier();
    asm volatile("" ::: "memory");
}

__global__ void qatten_prep1(const float* __restrict__ Wk, const float* __restrict__ bk,
                             float* __restrict__ WkT, float* __restrict__ bkSum)
{
    int idx = blockIdx.x * 256 + threadIdx.x;   // 0..8191
    int k = idx >> 7;          // 0..63
    int o = idx & 127;         // 0..127
    float s = 0.f;
#pragma unroll
    for (int h = 0; h < 4; ++h) s += Wk[h * (Od * QDd) + o * QDd + k];
    WkT[k * Od + o] = s;
    if (idx < QDd) {
        float t = 0.f;
#pragma unroll
        for (int h = 0; h < 4; ++h) t += bk[h * QDd + idx];
        bkSum[idx] = t;
    }
}

__global__ void qatten_prep2(const float* __restrict__ Wq2, const float* __restrict__ bq2,
                             const float* __restrict__ WkT, const float* __restrict__ bkSum,
                             float* __restrict__ M, float* __restrict__ v0,
                             float* __restrict__ m_beta, float* __restrict__ beta0)
{
    int idx = blockIdx.x * 256 + threadIdx.x;   // 0..16383
    int j = idx >> 7;          // 0..127
    int o = idx & 127;         // 0..127
    float acc = 0.f;
    for (int k = 0; k < QDd; ++k)
        acc = fmaf(Wq2[j * QDd + k], WkT[k * Od + o], acc);
    M[j * Od + o] = acc;
    if (idx < 128) {
        float a = 0.f;
        for (int k = 0; k < QDd; ++k) a = fmaf(bq2[k], WkT[k * Od + idx], a);
        v0[idx] = a;
    } else if (idx < 256) {
        const int jj = idx - 128;
        float a = 0.f;
        for (int k = 0; k < QDd; ++k) a = fmaf(Wq2[jj * QDd + k], bkSum[k], a);
        m_beta[jj] = a;
    }
    if (idx == 0) {
        float a = 0.f;
        for (int k = 0; k < QDd; ++k) a = fmaf(bq2[k], bkSum[k], a);
        beta0[0] = a;
    }
}

__global__ __launch_bounds__(256, 4) void qatten_fused(
    const float* __restrict__ qv, const float* __restrict__ st, const float* __restrict__ fs,
    const float* __restrict__ Wq1, const float* __restrict__ bq1,
    const float* __restrict__ Wc1, const float* __restrict__ bc1,
    const float* __restrict__ Wc2, const float* __restrict__ bc2,
    const float* __restrict__ M, const float* __restrict__ v0,
    const float* __restrict__ m_beta, const float* __restrict__ beta0p,
    float* __restrict__ out)
{
    __shared__ float s_lds[NB][Sd];     // 8 KB
    __shared__ float h_lds[NB][258];    // 8.06 KB (0-127: h1, 128-255: hc)
    __shared__ float v_lds[NB][Od];     // 4 KB
    __shared__ float q_lds[NB][Ad];     // 1 KB
    __shared__ float red_lds[NB][4];
    __shared__ float bias_lds[NB];      // total ~21.3 KB

    const int tid = threadIdx.x;
    const int b0 = blockIdx.x * NB;
    const int oq = tid & 31;            // float4 slot over O
    const int ag = tid >> 5;            // 0..7 agent group

    // ---- staging loads first (oldest -> retire before prefetches) ----
    const float4* sp = (const float4*)(st + (size_t)b0 * Sd);
    const float4 sstage0 = sp[tid];
    const float4 sstage1 = sp[tid + 256];
    const float  qstage  = qv[(size_t)b0 * Ad + tid];   // NB*Ad == 256

    // ---- f prefetch: b=0..3 (16 float4, 64 VGPR) — in flight through the MLP ----
    const float4* fbase = (const float4*)(fs + (size_t)b0 * (Ad * Od));
    float4 pf[16];
#pragma unroll
    for (int b = 0; b < 4; ++b)
#pragma unroll
        for (int r = 0; r < 4; ++r)
            pf[b * 4 + r] = fbase[(size_t)b * 1024 + (ag + 8 * r) * 32 + oq];

    ((float4*)&s_lds[0][0])[tid]       = sstage0;
    ((float4*)&s_lds[0][0])[tid + 256] = sstage1;
    (&q_lds[0][0])[tid] = qstage;
    barrier_lds();

    // ---- phase 2: h = relu(s @ [Wq1|Wc1] + bias); 1 col x 8 rows, K batched by 8 ----
    {
        const float* W  = (tid < 128) ? (Wq1 + tid) : (Wc1 + (tid - 128));
        const float  bb = (tid < 128) ? bq1[tid] : bc1[tid - 128];
        float acc[NB];
#pragma unroll
        for (int r = 0; r < NB; ++r) acc[r] = 0.f;
        for (int i = 0; i < Sd; i += 8) {
            float w[8];
#pragma unroll
            for (int u = 0; u < 8; ++u) w[u] = W[(size_t)(i + u) * 128];
#pragma unroll
            for (int r = 0; r < NB; ++r) {
                const float4 s0 = *(const float4*)&s_lds[r][i];
                const float4 s1 = *(const float4*)&s_lds[r][i + 4];
                float a = acc[r];
                a = fmaf(s0.x, w[0], a);
                a = fmaf(s0.y, w[1], a);
                a = fmaf(s0.z, w[2], a);
                a = fmaf(s0.w, w[3], a);
                a = fmaf(s1.x, w[4], a);
                a = fmaf(s1.y, w[5], a);
                a = fmaf(s1.z, w[6], a);
                a = fmaf(s1.w, w[7], a);
                acc[r] = a;
            }
        }
#pragma unroll
        for (int r = 0; r < NB; ++r)
            h_lds[r][tid] = fmaxf(acc[r] + bb, 0.f);
    }
    barrier_lds();

    // ---- phase 3: v[b] = h1[b]@M + v0; 1 col o x 4 rows ----
    {
        const int o = tid & 127;
        const int rg = (tid >> 7) * 4;   // rows rg..rg+3
        float acc[4] = {0.f, 0.f, 0.f, 0.f};
        for (int j = 0; j < 128; j += 4) {
            const float m0 = M[(size_t)(j + 0) * 128 + o];
            const float m1 = M[(size_t)(j + 1) * 128 + o];
            const float m2 = M[(size_t)(j + 2) * 128 + o];
            const float m3 = M[(size_t)(j + 3) * 128 + o];
#pragma unroll
            for (int r = 0; r < 4; ++r) {
                const float4 hv = *(const float4*)&h_lds[rg + r][j];  // broadcast
                float a = acc[r];
                a = fmaf(hv.x, m0, a);
                a = fmaf(hv.y, m1, a);
                a = fmaf(hv.z, m2, a);
                a = fmaf(hv.w, m3, a);
                acc[r] = a;
            }
        }
        const float v0o = v0[o];
#pragma unroll
        for (int r = 0; r < 4; ++r) v_lds[rg + r][o] = acc[r] + v0o;
    }

    // ---- f prefetch batch 2: b=4,5 (8 float4, 32 VGPR) ----
    float4 pf2[8];
#pragma unroll
    for (int b = 0; b < 2; ++b)
#pragma unroll
        for (int r = 0; r < 4; ++r)
            pf2[b * 4 + r] = fbase[(size_t)(4 + b) * 1024 + (ag + 8 * r) * 32 + oq];

    // ---- phase 5: bias[b]; 32 lanes per b (reads h_lds/q_lds, stable) ----
    {
        const int b = tid >> 5;
        const int i = tid & 31;
        float pb = 0.f, pc = 0.f;
#pragma unroll
        for (int t = 0; t < 4; ++t) {
            const int j = i + 32 * t;
            pb = fmaf(h_lds[b][j], m_beta[j], pb);
            pc = fmaf(h_lds[b][128 + j], Wc2[j], pc);
        }
        float pq = q_lds[b][i];
#pragma unroll
        for (int d = 16; d >= 1; d >>= 1) {
            pb += __shfl_down(pb, d, 32);
            pc += __shfl_down(pc, d, 32);
            pq += __shfl_down(pq, d, 32);
        }
        if (i == 0) bias_lds[b] = (pc + bc2[0]) + (pb + beta0p[0]) * pq;
    }
    barrier_lds();

    // ---- phase 6: stream dots; b0..3 from pf, b4,5 from pf2, b6,7 fresh ----
    {
        float accb[NB];
#pragma unroll
        for (int b = 0; b < 4; ++b) {
            const float4 v4 = *(const float4*)&v_lds[b][oq * 4];
            float s = 0.f;
#pragma unroll
            for (int r = 0; r < 4; ++r) {
                const float4 f4 = pf[b * 4 + r];
                float d = f4.x * v4.x;
                d = fmaf(f4.y, v4.y, d);
                d = fmaf(f4.z, v4.z, d);
                d = fmaf(f4.w, v4.w, d);
                s = fmaf(q_lds[b][ag + 8 * r], d, s);
            }
            accb[b] = s;
        }
#pragma unroll
        for (int b = 0; b < 2; ++b) {
            const float4 v4 = *(const float4*)&v_lds[4 + b][oq * 4];
            float s = 0.f;
#pragma unroll
            for (int r = 0; r < 4; ++r) {
                const float4 f4 = pf2[b * 4 + r];
                float d = f4.x * v4.x;
                d = fmaf(f4.y, v4.y, d);
                d = fmaf(f4.z, v4.z, d);
                d = fmaf(f4.w, v4.w, d);
                s = fmaf(q_lds[4 + b][ag + 8 * r], d, s);
            }
            accb[4 + b] = s;
        }
#pragma unroll
        for (int b = 6; b < 8; ++b) {
            const float4 v4 = *(const float4*)&v_lds[b][oq * 4];
            const float4* fb = fbase + (size_t)b * 1024;
            float s = 0.f;
#pragma unroll
            for (int r = 0; r < 4; ++r) {
                const float4 f4 = fb[(ag + 8 * r) * 32 + oq];
                float d = f4.x * v4.x;
                d = fmaf(f4.y, v4.y, d);
                d = fmaf(f4.z, v4.z, d);
                d = fmaf(f4.w, v4.w, d);
                s = fmaf(q_lds[b][ag + 8 * r], d, s);
            }
            accb[b] = s;
        }
        const int lane = tid & 63;
        const int wv = tid >> 6;
#pragma unroll
        for (int b = 0; b < NB; ++b) {
            float s = accb[b];
#pragma unroll
            for (int d = 32; d >= 1; d >>= 1) s += __shfl_xor(s, d);
            accb[b] = s;
        }
        if (lane == 0) {
#pragma unroll
            for (int b = 0; b < NB; ++b) red_lds[b][wv] = accb[b];
        }
    }
    barrier_lds();

    if (tid < NB) {
        out[b0 + tid] = red_lds[tid][0] + red_lds[tid][1] +
                        red_lds[tid][2] + red_lds[tid][3] + bias_lds[tid];
    }
}

extern "C" void kernel_launch(void* const* d_in, const int* in_sizes, int n_in,
                              void* d_out, int out_size, void* d_ws, size_t ws_size,
                              hipStream_t stream) {
    const float* qv  = (const float*)d_in[0];
    const float* st  = (const float*)d_in[1];
    const float* fs  = (const float*)d_in[2];
    const float* Wq1 = (const float*)d_in[3];
    const float* bq1 = (const float*)d_in[4];
    const float* Wq2 = (const float*)d_in[5];
    const float* bq2 = (const float*)d_in[6];
    const float* Wk  = (const float*)d_in[7];
    const float* bk  = (const float*)d_in[8];
    const float* Wc1 = (const float*)d_in[9];
    const float* bc1 = (const float*)d_in[10];
    const float* Wc2 = (const float*)d_in[11];
    const float* bc2 = (const float*)d_in[12];
    float* out = (float*)d_out;

    float* ws     = (float*)d_ws;
    float* WkT    = ws + WS_WKT;
    float* bkSum  = ws + WS_BKSUM;
    float* Mm     = ws + WS_M;
    float* v0     = ws + WS_V0;
    float* m_beta = ws + WS_MBETA;
    float* beta0  = ws + WS_BETA0;
    (void)ws_size; (void)in_sizes; (void)n_in; (void)out_size;

    qatten_prep1<<<32, 256, 0, stream>>>(Wk, bk, WkT, bkSum);
    qatten_prep2<<<64, 256, 0, stream>>>(Wq2, bq2, WkT, bkSum, Mm, v0, m_beta, beta0);
    qatten_fused<<<1024, 256, 0, stream>>>(qv, st, fs, Wq1, bq1, Wc1, bc1,
                                           Wc2, bc2, Mm, v0, m_beta, beta0, out);
}